// Round 1
// baseline (972.750 us; speedup 1.0000x reference)
//
#include <hip/hip_runtime.h>
#include <hip/hip_bf16.h>
#include <math.h>

namespace {

constexpr int Bb = 256, Jj = 21, Cc = 256, Hh = 8, Dd = 256;
constexpr int Mrows = Bb * Jj;      // 5376
constexpr int HD    = Hh * Dd;      // 2048
constexpr int KNN   = 8;

// workspace layout (float offsets)
constexpr size_t OFF_Q     = 0;
constexpr size_t OFF_K     = OFF_Q   + (size_t)Mrows * HD;
constexpr size_t OFF_V     = OFF_K   + (size_t)Mrows * HD;
constexpr size_t OFF_ATT   = OFF_V   + (size_t)Mrows * HD;
constexpr size_t OFF_H1    = OFF_ATT + (size_t)Mrows * HD;
constexpr size_t OFF_H2    = OFF_H1  + (size_t)Mrows * Cc;
constexpr size_t OFF_NBR   = OFF_H2  + (size_t)Mrows * Cc;     // ints
constexpr size_t OFF_STATS = OFF_NBR + (size_t)Mrows * KNN;    // 2 floats

} // namespace

// ---------------------------------------------------------------------------
// init: zero the 2 per-layer |h| sums
__global__ void zero_stats_kernel(float* stats) {
    if (threadIdx.x < 2) stats[threadIdx.x] = 0.0f;
}

// ---------------------------------------------------------------------------
// kNN: per batch, for each joint j rank all 21 joints by (d2, index) ascending
// and emit ranks 1..8. This EXACTLY matches jnp.argsort (stable) + [1:K+1],
// including the relu-induced exact-tie cases where rank 0 is not self.
__global__ __launch_bounds__(64)
void knn_kernel(const float* __restrict__ src, int ld, int* __restrict__ nbr) {
    int b = blockIdx.x;
    __shared__ float cs[Jj][3];
    int t = threadIdx.x;
    if (t < Jj) {
        const float* p = src + (size_t)(b * Jj + t) * ld;
        cs[t][0] = p[0]; cs[t][1] = p[1]; cs[t][2] = p[2];
    }
    __syncthreads();
    if (t < Jj) {
        float x = cs[t][0], y = cs[t][1], z = cs[t][2];
        float d2[Jj];
        #pragma unroll
        for (int jj = 0; jj < Jj; ++jj) {
            float dx = x - cs[jj][0];
            float dy = y - cs[jj][1];
            float dz = z - cs[jj][2];
            d2[jj] = dx * dx + dy * dy + dz * dz;
        }
        unsigned int used = 0u;
        int out_base = (b * Jj + t) * KNN;
        #pragma unroll
        for (int r = 0; r <= KNN; ++r) {   // 9 picks: rank 0 dropped
            int best = -1;
            float bd = INFINITY;
            #pragma unroll
            for (int jj = 0; jj < Jj; ++jj) {
                // ascending jj + strict '<' == smallest index on exact ties
                if (!((used >> jj) & 1u) && d2[jj] < bd) { bd = d2[jj]; best = jj; }
            }
            used |= (1u << best);
            if (r > 0) nbr[out_base + r - 1] = best;
        }
    }
}

// ---------------------------------------------------------------------------
// fp32 tiled GEMM: C[M,N] = A[M,K] @ W[K,N]   (all row-major, dims % tile == 0)
// BM=128 BN=64 BK=16, 256 threads, 8x4 per-thread tile.
__global__ __launch_bounds__(256)
void sgemm_kernel(const float* __restrict__ A, int lda,
                  const float* __restrict__ W, int ldw,
                  float* __restrict__ C, int ldc, int Ksize) {
    constexpr int BM = 128, BN = 64, BK = 16, TM = 8, TN = 4;
    __shared__ float As[BK][BM + 4];
    __shared__ float Ws[BK][BN + 4];

    int tid = threadIdx.x;
    int bm = blockIdx.x * BM;
    int bn = blockIdx.y * BN;
    int ty = tid / (BN / TN);          // 0..15
    int tx = tid % (BN / TN);          // 0..15
    int ar = tid / 2;                  // 0..127
    int ac = (tid % 2) * 8;            // 0 or 8
    int wr = tid / 16;                 // 0..15
    int wc = (tid % 16) * 4;           // 0..60

    float acc[TM][TN] = {};

    for (int k0 = 0; k0 < Ksize; k0 += BK) {
        const float* ap = A + (size_t)(bm + ar) * lda + k0 + ac;
        float4 av0 = *(const float4*)ap;
        float4 av1 = *(const float4*)(ap + 4);
        As[ac + 0][ar] = av0.x; As[ac + 1][ar] = av0.y;
        As[ac + 2][ar] = av0.z; As[ac + 3][ar] = av0.w;
        As[ac + 4][ar] = av1.x; As[ac + 5][ar] = av1.y;
        As[ac + 6][ar] = av1.z; As[ac + 7][ar] = av1.w;
        const float* wp = W + (size_t)(k0 + wr) * ldw + bn + wc;
        *(float4*)&Ws[wr][wc] = *(const float4*)wp;
        __syncthreads();
        #pragma unroll
        for (int kk = 0; kk < BK; ++kk) {
            const float4* a4 = (const float4*)&As[kk][ty * TM];
            float4 a0 = a4[0], a1 = a4[1];
            float4 bv = *(const float4*)&Ws[kk][tx * TN];
            float a[TM] = {a0.x, a0.y, a0.z, a0.w, a1.x, a1.y, a1.z, a1.w};
            float bb[TN] = {bv.x, bv.y, bv.z, bv.w};
            #pragma unroll
            for (int i = 0; i < TM; ++i)
                #pragma unroll
                for (int j = 0; j < TN; ++j)
                    acc[i][j] += a[i] * bb[j];
        }
        __syncthreads();
    }
    #pragma unroll
    for (int i = 0; i < TM; ++i) {
        float4 o = {acc[i][0], acc[i][1], acc[i][2], acc[i][3]};
        *(float4*)(C + (size_t)(bm + ty * TM + i) * ldc + bn + tx * TN) = o;
    }
}

// ---------------------------------------------------------------------------
// attention: one wave per (b, j, head). scores -> leaky_relu -> softmax over
// K=8 neighbors -> weighted V sum.
__global__ __launch_bounds__(64)
void attn_kernel(const float* __restrict__ Q, const float* __restrict__ Kb,
                 const float* __restrict__ Vb, const int* __restrict__ nbr,
                 float* __restrict__ att) {
    int gid = blockIdx.x;
    int h = gid & 7;
    int row = gid >> 3;
    int b = row / Jj;
    int lane = threadIdx.x;

    const float4 q4 = *(const float4*)(Q + (size_t)row * HD + h * Dd + lane * 4);
    const int* np_ = nbr + row * KNN;

    float sc[KNN];
    int nb[KNN];
    #pragma unroll
    for (int k = 0; k < KNN; ++k) {
        int n = np_[k];
        nb[k] = n;
        const float4 k4 = *(const float4*)(Kb + (size_t)(b * Jj + n) * HD + h * Dd + lane * 4);
        float p = q4.x * k4.x + q4.y * k4.y + q4.z * k4.z + q4.w * k4.w;
        #pragma unroll
        for (int s = 32; s > 0; s >>= 1) p += __shfl_xor(p, s);
        sc[k] = p;
    }
    float mx = -INFINITY;
    #pragma unroll
    for (int k = 0; k < KNN; ++k) {
        float s = sc[k] * 0.0625f;               // / sqrt(256)
        s = (s >= 0.0f) ? s : 0.2f * s;          // leaky_relu 0.2
        sc[k] = s;
        mx = fmaxf(mx, s);
    }
    float den = 0.0f;
    #pragma unroll
    for (int k = 0; k < KNN; ++k) { sc[k] = expf(sc[k] - mx); den += sc[k]; }
    float inv = 1.0f / den;

    float4 o = {0.f, 0.f, 0.f, 0.f};
    #pragma unroll
    for (int k = 0; k < KNN; ++k) {
        const float4 v4 = *(const float4*)(Vb + (size_t)(b * Jj + nb[k]) * HD + h * Dd + lane * 4);
        float w = sc[k] * inv;
        o.x += w * v4.x; o.y += w * v4.y; o.z += w * v4.z; o.w += w * v4.w;
    }
    *(float4*)(att + (size_t)row * HD + h * Dd + lane * 4) = o;
}

// ---------------------------------------------------------------------------
// fused epilogue GEMM: hout = relu(att@wp + h@wsl + h0@wsk); stat += sum(hout)
__global__ __launch_bounds__(256)
void fused_out_kernel(const float* __restrict__ att, const float* __restrict__ wp,
                      const float* __restrict__ h,   const float* __restrict__ wsl,
                      const float* __restrict__ h0,  const float* __restrict__ wsk,
                      float* __restrict__ hout, float* __restrict__ stat) {
    constexpr int BM = 128, BN = 64, BK = 16, TM = 8, TN = 4;
    __shared__ float As[BK][BM + 4];
    __shared__ float Ws[BK][BN + 4];
    __shared__ float red[4];

    int tid = threadIdx.x;
    int bm = blockIdx.x * BM;
    int bn = blockIdx.y * BN;
    int ty = tid / (BN / TN), tx = tid % (BN / TN);
    int ar = tid / 2, ac = (tid % 2) * 8;
    int wr = tid / 16, wc = (tid % 16) * 4;

    float acc[TM][TN] = {};

    const float* Aseg[3] = {att, h, h0};
    const int    ldaseg[3] = {HD, Cc, Cc};
    const float* Wseg[3] = {wp, wsl, wsk};
    const int    kseg[3] = {HD, Cc, Cc};

    for (int seg = 0; seg < 3; ++seg) {
        const float* A = Aseg[seg];
        const float* W = Wseg[seg];
        int lda = ldaseg[seg], Ksize = kseg[seg];
        for (int k0 = 0; k0 < Ksize; k0 += BK) {
            const float* ap = A + (size_t)(bm + ar) * lda + k0 + ac;
            float4 av0 = *(const float4*)ap;
            float4 av1 = *(const float4*)(ap + 4);
            As[ac + 0][ar] = av0.x; As[ac + 1][ar] = av0.y;
            As[ac + 2][ar] = av0.z; As[ac + 3][ar] = av0.w;
            As[ac + 4][ar] = av1.x; As[ac + 5][ar] = av1.y;
            As[ac + 6][ar] = av1.z; As[ac + 7][ar] = av1.w;
            const float* wpp = W + (size_t)(k0 + wr) * Cc + bn + wc;
            *(float4*)&Ws[wr][wc] = *(const float4*)wpp;
            __syncthreads();
            #pragma unroll
            for (int kk = 0; kk < BK; ++kk) {
                const float4* a4 = (const float4*)&As[kk][ty * TM];
                float4 a0 = a4[0], a1 = a4[1];
                float4 bv = *(const float4*)&Ws[kk][tx * TN];
                float a[TM] = {a0.x, a0.y, a0.z, a0.w, a1.x, a1.y, a1.z, a1.w};
                float bb[TN] = {bv.x, bv.y, bv.z, bv.w};
                #pragma unroll
                for (int i = 0; i < TM; ++i)
                    #pragma unroll
                    for (int j = 0; j < TN; ++j)
                        acc[i][j] += a[i] * bb[j];
            }
            __syncthreads();
        }
    }

    float bsum = 0.0f;
    #pragma unroll
    for (int i = 0; i < TM; ++i) {
        float4 o;
        o.x = fmaxf(acc[i][0], 0.0f); o.y = fmaxf(acc[i][1], 0.0f);
        o.z = fmaxf(acc[i][2], 0.0f); o.w = fmaxf(acc[i][3], 0.0f);
        bsum += o.x + o.y + o.z + o.w;
        *(float4*)(hout + (size_t)(bm + ty * TM + i) * Cc + bn + tx * TN) = o;
    }
    // block reduce of bsum (relu output >= 0 so sum == sum of |.|)
    #pragma unroll
    for (int s = 32; s > 0; s >>= 1) bsum += __shfl_xor(bsum, s);
    int wave = tid >> 6;
    if ((tid & 63) == 0) red[wave] = bsum;
    __syncthreads();
    if (tid == 0) {
        float t = red[0] + red[1] + red[2] + red[3];
        atomicAdd(stat, t);
    }
}

// ---------------------------------------------------------------------------
// final: coords = h@fc_w + fc_b ; out[M*3] = alphas
__global__ __launch_bounds__(64)
void final_kernel(const float* __restrict__ h, const float* __restrict__ fcw,
                  const float* __restrict__ fcb, const float* __restrict__ stats,
                  float* __restrict__ out) {
    int row = blockIdx.x;
    int lane = threadIdx.x;
    const float4 hv = *(const float4*)(h + (size_t)row * Cc + lane * 4);
    float a0 = 0.f, a1 = 0.f, a2 = 0.f;
    const float hx[4] = {hv.x, hv.y, hv.z, hv.w};
    #pragma unroll
    for (int i = 0; i < 4; ++i) {
        int c = lane * 4 + i;
        a0 += hx[i] * fcw[c * 3 + 0];
        a1 += hx[i] * fcw[c * 3 + 1];
        a2 += hx[i] * fcw[c * 3 + 2];
    }
    #pragma unroll
    for (int s = 32; s > 0; s >>= 1) {
        a0 += __shfl_xor(a0, s);
        a1 += __shfl_xor(a1, s);
        a2 += __shfl_xor(a2, s);
    }
    if (lane == 0) {
        out[row * 3 + 0] = a0 + fcb[0];
        out[row * 3 + 1] = a1 + fcb[1];
        out[row * 3 + 2] = a2 + fcb[2];
        if (row == 0)
            out[(size_t)Mrows * 3] =
                (stats[0] + stats[1]) * (0.5f / ((float)Mrows * (float)Cc));
    }
}

// ---------------------------------------------------------------------------
extern "C" void kernel_launch(void* const* d_in, const int* in_sizes, int n_in,
                              void* d_out, int out_size, void* d_ws, size_t ws_size,
                              hipStream_t stream) {
    (void)in_sizes; (void)n_in; (void)out_size; (void)ws_size;

    const float* jf     = (const float*)d_in[0];   // (B,J,256)
    const float* wq     = (const float*)d_in[1];   // (2,256,2048)
    const float* wk     = (const float*)d_in[2];
    const float* wv     = (const float*)d_in[3];
    const float* wp     = (const float*)d_in[4];   // (2,2048,256)
    const float* wsw    = (const float*)d_in[5];   // (2,256,256)
    const float* wskip0 = (const float*)d_in[6];   // (256,256)
    const float* fcw    = (const float*)d_in[7];   // (256,3)
    const float* fcb    = (const float*)d_in[8];   // (3,)
    float* out = (float*)d_out;

    float* ws = (float*)d_ws;
    float* Q   = ws + OFF_Q;
    float* Kb  = ws + OFF_K;
    float* Vb  = ws + OFF_V;
    float* att = ws + OFF_ATT;
    float* h1  = ws + OFF_H1;
    float* h2  = ws + OFF_H2;
    int*   nbr = (int*)(ws + OFF_NBR);
    float* stats = ws + OFF_STATS;

    dim3 gemmGridQKV(Mrows / 128, HD / 64);   // (42, 32)
    dim3 gemmGridOut(Mrows / 128, Cc / 64);   // (42, 4)

    zero_stats_kernel<<<1, 64, 0, stream>>>(stats);

    // ---- layer 0 (h = jf, h0 = jf) ----
    knn_kernel<<<Bb, 64, 0, stream>>>(jf, Cc, nbr);
    sgemm_kernel<<<gemmGridQKV, 256, 0, stream>>>(jf, Cc, wq, HD, Q,  HD, Cc);
    sgemm_kernel<<<gemmGridQKV, 256, 0, stream>>>(jf, Cc, wk, HD, Kb, HD, Cc);
    sgemm_kernel<<<gemmGridQKV, 256, 0, stream>>>(jf, Cc, wv, HD, Vb, HD, Cc);
    attn_kernel<<<Mrows * Hh, 64, 0, stream>>>(Q, Kb, Vb, nbr, att);
    fused_out_kernel<<<gemmGridOut, 256, 0, stream>>>(
        att, wp, jf, wsw, jf, wskip0, h1, &stats[0]);

    // ---- layer 1 (h = h1, h0 = jf) ----
    const float* wq1 = wq + (size_t)Cc * HD;
    const float* wk1 = wk + (size_t)Cc * HD;
    const float* wv1 = wv + (size_t)Cc * HD;
    const float* wp1 = wp + (size_t)HD * Cc;
    const float* ws1 = wsw + (size_t)Cc * Cc;
    knn_kernel<<<Bb, 64, 0, stream>>>(h1, Cc, nbr);
    sgemm_kernel<<<gemmGridQKV, 256, 0, stream>>>(h1, Cc, wq1, HD, Q,  HD, Cc);
    sgemm_kernel<<<gemmGridQKV, 256, 0, stream>>>(h1, Cc, wk1, HD, Kb, HD, Cc);
    sgemm_kernel<<<gemmGridQKV, 256, 0, stream>>>(h1, Cc, wv1, HD, Vb, HD, Cc);
    attn_kernel<<<Mrows * Hh, 64, 0, stream>>>(Q, Kb, Vb, nbr, att);
    fused_out_kernel<<<gemmGridOut, 256, 0, stream>>>(
        att, wp1, h1, ws1, jf, wskip0, h2, &stats[1]);

    // ---- final ----
    final_kernel<<<Mrows, 64, 0, stream>>>(h2, fcw, fcb, stats, out);
}

// Round 2
// 438.817 us; speedup vs baseline: 2.2168x; 2.2168x over previous
//
#include <hip/hip_runtime.h>
#include <hip/hip_bf16.h>
#include <math.h>

namespace {
constexpr int Bb = 256, Jj = 21, Cc = 256, Hh = 8, Dd = 256;
constexpr int Mrows = Bb * Jj;      // 5376
constexpr int HD    = Hh * Dd;      // 2048
constexpr int QKVN  = 3 * HD;       // 6144
constexpr int KNN   = 8;
constexpr int KFUSE = HD + Cc + Cc; // 2560

// ---- workspace byte offsets (all 256-aligned) ----
constexpr size_t OFF_QKV   = 0;                                   // bf16 5376x6144
constexpr size_t OFF_ATT   = OFF_QKV   + (size_t)Mrows*QKVN*2;    // bf16 5376x2048
constexpr size_t OFF_T     = OFF_ATT   + (size_t)Mrows*HD*2;      // f32  5376x2048
constexpr size_t OFF_G     = OFF_T     + (size_t)Mrows*HD*4;      // f32  256x2048
constexpr size_t OFF_JFB   = OFF_G     + (size_t)Cc*HD*4;         // bf16 5376x256
constexpr size_t OFF_H1B   = OFF_JFB   + (size_t)Mrows*Cc*2;      // bf16 5376x256
constexpr size_t OFF_H2F   = OFF_H1B   + (size_t)Mrows*Cc*2;      // f32  5376x256
constexpr size_t OFF_WQKVT = OFF_H2F   + (size_t)Mrows*Cc*4;      // bf16 2x6144x256
constexpr size_t OFF_FBT   = OFF_WQKVT + (size_t)2*QKVN*Cc*2;     // bf16 2x256x2560
constexpr size_t OFF_WVP   = OFF_FBT   + (size_t)2*Cc*KFUSE*2;    // f32  8x256x3
constexpr size_t OFF_VPROJ = OFF_WVP   + (size_t)Hh*Cc*3*4;       // f32  5376x24
constexpr size_t OFF_CRD   = OFF_VPROJ + (size_t)Mrows*24*4;      // f32  5376x3
constexpr size_t OFF_NBR0  = OFF_CRD   + (size_t)Mrows*3*4 + 160; // int  5376x8
constexpr size_t OFF_NBR1  = OFF_NBR0  + (size_t)Mrows*KNN*4;
constexpr size_t OFF_STAT  = OFF_NBR1  + (size_t)Mrows*KNN*4;     // 2 f32
} // namespace

typedef short short8 __attribute__((ext_vector_type(8)));
typedef float f32x4 __attribute__((ext_vector_type(4)));

__device__ __forceinline__ unsigned short f2bf(float x) {
    unsigned int u = __float_as_uint(x);
    u = u + 0x7fffu + ((u >> 16) & 1u);            // round-to-nearest-even
    return (unsigned short)(u >> 16);
}
__device__ __forceinline__ float bf2f(unsigned short b) {
    return __uint_as_float(((unsigned int)b) << 16);
}

// ---------------------------------------------------------------------------
__global__ void zero_stats_kernel(float* stats) {
    if (threadIdx.x < 2) stats[threadIdx.x] = 0.0f;
}

// ---------------------------------------------------------------------------
// exact stable-argsort kNN: ranks 1..8 by (d2, index) ascending
__global__ __launch_bounds__(64)
void knn_kernel(const float* __restrict__ src, int ld, int* __restrict__ nbr) {
    int b = blockIdx.x;
    __shared__ float cs[Jj][3];
    int t = threadIdx.x;
    if (t < Jj) {
        const float* p = src + (size_t)(b * Jj + t) * ld;
        cs[t][0] = p[0]; cs[t][1] = p[1]; cs[t][2] = p[2];
    }
    __syncthreads();
    if (t < Jj) {
        float x = cs[t][0], y = cs[t][1], z = cs[t][2];
        float d2[Jj];
        #pragma unroll
        for (int jj = 0; jj < Jj; ++jj) {
            float dx = x - cs[jj][0], dy = y - cs[jj][1], dz = z - cs[jj][2];
            d2[jj] = dx*dx + dy*dy + dz*dz;
        }
        unsigned int used = 0u;
        int out_base = (b * Jj + t) * KNN;
        #pragma unroll
        for (int r = 0; r <= KNN; ++r) {
            int best = -1; float bd = INFINITY;
            #pragma unroll
            for (int jj = 0; jj < Jj; ++jj)
                if (!((used >> jj) & 1u) && d2[jj] < bd) { bd = d2[jj]; best = jj; }
            used |= (1u << best);
            if (r > 0) nbr[out_base + r - 1] = best;
        }
    }
}

// ---------------------------------------------------------------------------
// fp32 -> bf16 elementwise (n4 = n/4)
__global__ __launch_bounds__(256)
void cvt_bf16_kernel(const float* __restrict__ in, unsigned short* __restrict__ out, int n4) {
    int i = blockIdx.x * 256 + threadIdx.x;
    if (i < n4) {
        float4 v = ((const float4*)in)[i];
        ushort4 o; o.x = f2bf(v.x); o.y = f2bf(v.y); o.z = f2bf(v.z); o.w = f2bf(v.w);
        ((ushort4*)out)[i] = o;
    }
}

// ---------------------------------------------------------------------------
// out[n][k] = bf16(in[k][n]); 32x32 tiles. grid = (N/32, K/32)
__global__ __launch_bounds__(256)
void transpose_cvt_kernel(const float* __restrict__ in, int ldin,
                          unsigned short* __restrict__ out, int ldout) {
    __shared__ float t[32][33];
    int n0 = blockIdx.x * 32, k0 = blockIdx.y * 32;
    int r = threadIdx.x >> 3;
    int c4 = (threadIdx.x & 7) * 4;
    float4 v = *(const float4*)&in[(size_t)(k0 + r) * ldin + n0 + c4];
    t[r][c4+0] = v.x; t[r][c4+1] = v.y; t[r][c4+2] = v.z; t[r][c4+3] = v.w;
    __syncthreads();
    ushort4 o;
    o.x = f2bf(t[c4+0][r]); o.y = f2bf(t[c4+1][r]);
    o.z = f2bf(t[c4+2][r]); o.w = f2bf(t[c4+3][r]);
    *(ushort4*)&out[(size_t)(n0 + r) * ldout + k0 + c4] = o;
}

// ---------------------------------------------------------------------------
// G[c][h*256+c'] = sum_d wq[c][h*256+d] * wk[c'][h*256+d]   (fp32, exact path)
// grid (8, 64): block handles head h, rows c = cg*4..cg*4+3
__global__ __launch_bounds__(64)
void g_kernel(const float* __restrict__ wq, const float* __restrict__ wk,
              float* __restrict__ G) {
    int h = blockIdx.x, cg = blockIdx.y;
    __shared__ float q[4][256];
    int l = threadIdx.x;
    #pragma unroll
    for (int ci = 0; ci < 4; ++ci)
        *(float4*)&q[ci][l*4] = *(const float4*)&wq[(size_t)(cg*4+ci)*HD + h*256 + l*4];
    __syncthreads();
    #pragma unroll
    for (int i = 0; i < 4; ++i) {
        int cp = l + i*64;
        const float* kr = &wk[(size_t)cp*HD + h*256];
        float a0=0,a1=0,a2=0,a3=0;
        for (int d = 0; d < 256; d += 4) {
            float4 kv = *(const float4*)&kr[d];
            a0 += q[0][d]*kv.x + q[0][d+1]*kv.y + q[0][d+2]*kv.z + q[0][d+3]*kv.w;
            a1 += q[1][d]*kv.x + q[1][d+1]*kv.y + q[1][d+2]*kv.z + q[1][d+3]*kv.w;
            a2 += q[2][d]*kv.x + q[2][d+1]*kv.y + q[2][d+2]*kv.z + q[2][d+3]*kv.w;
            a3 += q[3][d]*kv.x + q[3][d+1]*kv.y + q[3][d+2]*kv.z + q[3][d+3]*kv.w;
        }
        G[(size_t)(cg*4+0)*HD + h*256 + cp] = a0;
        G[(size_t)(cg*4+1)*HD + h*256 + cp] = a1;
        G[(size_t)(cg*4+2)*HD + h*256 + cp] = a2;
        G[(size_t)(cg*4+3)*HD + h*256 + cp] = a3;
    }
}

// ---------------------------------------------------------------------------
// Wvp[h][e][c] = sum_d wv[e][h*256+d] * wp[h*256+d][c], c<3. grid (8), 256 thr
__global__ __launch_bounds__(256)
void wvp_kernel(const float* __restrict__ wv, const float* __restrict__ wp,
                float* __restrict__ Wvp) {
    int h = blockIdx.x;
    __shared__ float wpc[256][3];
    int t = threadIdx.x;
    const float* p = &wp[(size_t)(h*256 + t) * Cc];
    wpc[t][0] = p[0]; wpc[t][1] = p[1]; wpc[t][2] = p[2];
    __syncthreads();
    const float* vr = &wv[(size_t)t*HD + h*256];
    float a0=0, a1=0, a2=0;
    for (int d = 0; d < 256; ++d) {
        float v = vr[d];
        a0 += v*wpc[d][0]; a1 += v*wpc[d][1]; a2 += v*wpc[d][2];
    }
    float* o = &Wvp[(size_t)(h*256 + t) * 3];
    o[0]=a0; o[1]=a1; o[2]=a2;
}

// ---------------------------------------------------------------------------
// vproj[j][h*3+c] = sum_e h0[j][e] * Wvp[h][e][c].  grid (5376), 64 thr
__global__ __launch_bounds__(64)
void vproj_kernel(const float* __restrict__ h0, const float* __restrict__ Wvp,
                  float* __restrict__ vproj) {
    int j = blockIdx.x;
    __shared__ float hr[256];
    int l = threadIdx.x;
    *(float4*)&hr[l*4] = *(const float4*)&h0[(size_t)j*Cc + l*4];
    __syncthreads();
    if (l < 24) {
        int h = l / 3, c = l % 3;
        const float* wvp = &Wvp[(size_t)h*256*3 + c];
        float a = 0;
        for (int e = 0; e < 256; ++e) a += hr[e] * wvp[e*3];
        vproj[(size_t)j*24 + l] = a;
    }
}

// ---------------------------------------------------------------------------
// precise layer-0 coords: per row i, softmax(leaky(T_i . h0_nbr /16)) over K,
// coords = relu(sum_k w * vproj[nbr] + h0_i.(ws0+wskip0)[:,c])
__global__ __launch_bounds__(64)
void precise_kernel(const float* __restrict__ T, const float* __restrict__ h0,
                    const int* __restrict__ nbr, const float* __restrict__ vproj,
                    const float* __restrict__ wsl, const float* __restrict__ wsk,
                    float* __restrict__ coords) {
    int i = blockIdx.x;
    int b = i / Jj;
    int l = threadIdx.x;
    __shared__ float Ts[8][260];
    __shared__ float nb[8][260];
    __shared__ float hi[256];
    #pragma unroll
    for (int u = 0; u < 8; ++u) {
        int idx = u*64 + l;
        float4 v = *(const float4*)&T[(size_t)i*HD + idx*4];
        int hh = idx >> 6, dd = (idx & 63) * 4;
        *(float4*)&Ts[hh][dd] = v;
    }
    *(float4*)&hi[l*4] = *(const float4*)&h0[(size_t)i*Cc + l*4];
    int kq = l >> 3, s = l & 7;
    int njs = nbr[i*KNN + kq];
    const float* nrow = &h0[(size_t)(b*Jj + njs)*Cc];
    #pragma unroll
    for (int u = 0; u < 8; ++u)
        *(float4*)&nb[kq][(s*8+u)*4] = *(const float4*)&nrow[(s*8+u)*4];
    __syncthreads();

    int k = l >> 3, h = l & 7;
    float sacc = 0;
    for (int d = 0; d < 256; ++d) sacc += Ts[h][d] * nb[k][d];
    float sc = sacc * 0.0625f;
    sc = (sc >= 0.0f) ? sc : 0.2f * sc;
    float m = sc;
    m = fmaxf(m, __shfl_xor(m, 8));
    m = fmaxf(m, __shfl_xor(m, 16));
    m = fmaxf(m, __shfl_xor(m, 32));
    float e = expf(sc - m);
    float den = e;
    den += __shfl_xor(den, 8); den += __shfl_xor(den, 16); den += __shfl_xor(den, 32);
    float w = e / den;

    int njk = nbr[i*KNN + k];
    const float* vp = &vproj[(size_t)(b*Jj + njk)*24 + h*3];
    float t0 = w * vp[0], t1 = w * vp[1], t2 = w * vp[2];
    #pragma unroll
    for (int u = 0; u < 4; ++u) {
        int e4 = l*4 + u;
        float hv = hi[e4];
        const float* w1 = &wsl[(size_t)e4*Cc];
        const float* w2 = &wsk[(size_t)e4*Cc];
        t0 += hv * (w1[0] + w2[0]);
        t1 += hv * (w1[1] + w2[1]);
        t2 += hv * (w1[2] + w2[2]);
    }
    #pragma unroll
    for (int sft = 1; sft < 64; sft <<= 1) {
        t0 += __shfl_xor(t0, sft); t1 += __shfl_xor(t1, sft); t2 += __shfl_xor(t2, sft);
    }
    if (l == 0) {
        coords[i*3+0] = fmaxf(t0, 0.0f);
        coords[i*3+1] = fmaxf(t1, 0.0f);
        coords[i*3+2] = fmaxf(t2, 0.0f);
    }
}

// ---------------------------------------------------------------------------
// fp32 tiled GEMM (kept for T = h0 @ G): BM=128 BN=64 BK=16
__global__ __launch_bounds__(256)
void sgemm_kernel(const float* __restrict__ A, int lda,
                  const float* __restrict__ W, int ldw,
                  float* __restrict__ C, int ldc, int Ksize) {
    constexpr int BM = 128, BN = 64, BK = 16, TM = 8, TN = 4;
    __shared__ float As[BK][BM + 4];
    __shared__ float Ws[BK][BN + 4];
    int tid = threadIdx.x;
    int bm = blockIdx.x * BM, bn = blockIdx.y * BN;
    int ty = tid / (BN/TN), tx = tid % (BN/TN);
    int ar = tid / 2, ac = (tid % 2) * 8;
    int wr = tid / 16, wc = (tid % 16) * 4;
    float acc[TM][TN] = {};
    for (int k0 = 0; k0 < Ksize; k0 += BK) {
        const float* ap = A + (size_t)(bm + ar)*lda + k0 + ac;
        float4 a0v = *(const float4*)ap, a1v = *(const float4*)(ap + 4);
        As[ac+0][ar]=a0v.x; As[ac+1][ar]=a0v.y; As[ac+2][ar]=a0v.z; As[ac+3][ar]=a0v.w;
        As[ac+4][ar]=a1v.x; As[ac+5][ar]=a1v.y; As[ac+6][ar]=a1v.z; As[ac+7][ar]=a1v.w;
        *(float4*)&Ws[wr][wc] = *(const float4*)(W + (size_t)(k0+wr)*ldw + bn + wc);
        __syncthreads();
        #pragma unroll
        for (int kk = 0; kk < BK; ++kk) {
            const float4* a4 = (const float4*)&As[kk][ty*TM];
            float4 av0 = a4[0], av1 = a4[1];
            float4 bv = *(const float4*)&Ws[kk][tx*TN];
            float a[TM] = {av0.x,av0.y,av0.z,av0.w,av1.x,av1.y,av1.z,av1.w};
            float bb[TN] = {bv.x,bv.y,bv.z,bv.w};
            #pragma unroll
            for (int i = 0; i < TM; ++i)
                #pragma unroll
                for (int j = 0; j < TN; ++j)
                    acc[i][j] += a[i]*bb[j];
        }
        __syncthreads();
    }
    #pragma unroll
    for (int i = 0; i < TM; ++i) {
        float4 o = {acc[i][0], acc[i][1], acc[i][2], acc[i][3]};
        *(float4*)(C + (size_t)(bm + ty*TM + i)*ldc + bn + tx*TN) = o;
    }
}

// ---------------------------------------------------------------------------
// bf16 MFMA GEMM, B^T input ([N][K]), segmented A along K, fp32 accum.
// 256 threads = 4 waves in 2x2; per-wave tile (BM/2)x(BN/2).
template<int BM, int BN, int BK, int NSEG, bool RELU_STATS, bool OUT_BF16>
__global__ __launch_bounds__(256)
void gemm_bt_kernel(const unsigned short* __restrict__ A0, int lda0, int klen0,
                    const unsigned short* __restrict__ A1, int lda1, int klen1,
                    const unsigned short* __restrict__ A2, int lda2, int klen2,
                    const unsigned short* __restrict__ Bt, int ldb,
                    void* __restrict__ Cv, int ldc, float* __restrict__ stat) {
    constexpr int WM = BM/2, WN = BN/2;
    constexpr int MW = WM/16, NW = WN/16, KW = BK/32;
    constexpr int CHUNK = BM*BK/8;       // 16B chunks per tile (BM==BN)
    constexpr int KB8 = BK/8;
    __shared__ unsigned short As[BM*BK];
    __shared__ unsigned short Bs[BN*BK];
    __shared__ float red[4];

    int tid = threadIdx.x;
    int wid = tid >> 6, lane = tid & 63;
    int wr = wid >> 1, wc = wid & 1;
    int bm = blockIdx.x * BM, bn = blockIdx.y * BN;

    f32x4 acc[MW][NW];
    #pragma unroll
    for (int m = 0; m < MW; ++m)
        #pragma unroll
        for (int n = 0; n < NW; ++n)
            acc[m][n] = (f32x4){0.f, 0.f, 0.f, 0.f};

    const unsigned short* Aseg[3] = {A0, A1, A2};
    const int ldas[3] = {lda0, lda1, lda2};
    const int klens[3] = {klen0, klen1, klen2};

    int kglob = 0;
    for (int seg = 0; seg < NSEG; ++seg) {
        const unsigned short* A = Aseg[seg];
        const int lda = ldas[seg];
        const int klen = klens[seg];
        for (int k0 = 0; k0 < klen; k0 += BK) {
            #pragma unroll
            for (int it = 0; it < CHUNK/256; ++it) {
                int c = tid + it*256;
                int row = c / KB8, kp = c % KB8;
                __builtin_amdgcn_global_load_lds(
                    (const __attribute__((address_space(1))) unsigned int*)
                        (A + (size_t)(bm + row)*lda + k0 + kp*8),
                    (__attribute__((address_space(3))) unsigned int*)(As + c*8),
                    16, 0, 0);
            }
            #pragma unroll
            for (int it = 0; it < CHUNK/256; ++it) {
                int c = tid + it*256;
                int row = c / KB8, kp = c % KB8;
                __builtin_amdgcn_global_load_lds(
                    (const __attribute__((address_space(1))) unsigned int*)
                        (Bt + (size_t)(bn + row)*ldb + kglob + k0 + kp*8),
                    (__attribute__((address_space(3))) unsigned int*)(Bs + c*8),
                    16, 0, 0);
            }
            __syncthreads();
            #pragma unroll
            for (int kp = 0; kp < KW; ++kp) {
                short8 af[MW], bf[NW];
                #pragma unroll
                for (int m = 0; m < MW; ++m)
                    af[m] = *(const short8*)&As[(wr*WM + m*16 + (lane & 15))*BK
                                               + kp*32 + (lane >> 4)*8];
                #pragma unroll
                for (int n = 0; n < NW; ++n)
                    bf[n] = *(const short8*)&Bs[(wc*WN + n*16 + (lane & 15))*BK
                                               + kp*32 + (lane >> 4)*8];
                #pragma unroll
                for (int m = 0; m < MW; ++m)
                    #pragma unroll
                    for (int n = 0; n < NW; ++n)
                        acc[m][n] = __builtin_amdgcn_mfma_f32_16x16x32_bf16(
                            af[m], bf[n], acc[m][n], 0, 0, 0);
            }
            __syncthreads();
        }
        kglob += klen;
    }

    // epilogue: C/D layout col=lane&15, row=(lane>>4)*4+j
    int cr = (lane >> 4)*4, cc = lane & 15;
    float bsum = 0.0f;
    #pragma unroll
    for (int m = 0; m < MW; ++m)
        #pragma unroll
        for (int n = 0; n < NW; ++n)
            #pragma unroll
            for (int j = 0; j < 4; ++j) {
                float v = acc[m][n][j];
                if (RELU_STATS) { v = fmaxf(v, 0.0f); bsum += v; }
                size_t row = bm + wr*WM + m*16 + cr + j;
                size_t col = bn + wc*WN + n*16 + cc;
                if (OUT_BF16) ((unsigned short*)Cv)[row*ldc + col] = f2bf(v);
                else          ((float*)Cv)[row*ldc + col] = v;
            }
    if (RELU_STATS) {
        #pragma unroll
        for (int sft = 1; sft < 64; sft <<= 1) bsum += __shfl_xor(bsum, sft);
        if (lane == 0) red[wid] = bsum;
        __syncthreads();
        if (tid == 0) atomicAdd(stat, red[0] + red[1] + red[2] + red[3]);
    }
}

// ---------------------------------------------------------------------------
// attention (fast path, bf16 in/out): one wave per (row, head)
__global__ __launch_bounds__(64)
void attn_kernel(const unsigned short* __restrict__ QKV,
                 const int* __restrict__ nbr, unsigned short* __restrict__ att) {
    int gid = blockIdx.x;
    int h = gid & 7, row = gid >> 3, b = row / Jj;
    int lane = threadIdx.x;
    const size_t rbase = (size_t)row * QKVN + h * Dd + lane * 4;
    ushort4 qu = *(const ushort4*)&QKV[rbase];
    float q0 = bf2f(qu.x), q1 = bf2f(qu.y), q2 = bf2f(qu.z), q3 = bf2f(qu.w);
    const int* np_ = nbr + row * KNN;

    float sc[KNN]; int nb[KNN];
    #pragma unroll
    for (int k = 0; k < KNN; ++k) {
        int n = np_[k]; nb[k] = n;
        ushort4 ku = *(const ushort4*)&QKV[(size_t)(b*Jj + n)*QKVN + HD + h*Dd + lane*4];
        float p = q0*bf2f(ku.x) + q1*bf2f(ku.y) + q2*bf2f(ku.z) + q3*bf2f(ku.w);
        #pragma unroll
        for (int s = 32; s > 0; s >>= 1) p += __shfl_xor(p, s);
        sc[k] = p;
    }
    float mx = -INFINITY;
    #pragma unroll
    for (int k = 0; k < KNN; ++k) {
        float s = sc[k] * 0.0625f;
        s = (s >= 0.0f) ? s : 0.2f * s;
        sc[k] = s; mx = fmaxf(mx, s);
    }
    float den = 0.0f;
    #pragma unroll
    for (int k = 0; k < KNN; ++k) { sc[k] = expf(sc[k] - mx); den += sc[k]; }
    float inv = 1.0f / den;
    float o0=0,o1=0,o2=0,o3=0;
    #pragma unroll
    for (int k = 0; k < KNN; ++k) {
        ushort4 vu = *(const ushort4*)&QKV[(size_t)(b*Jj + nb[k])*QKVN + 2*HD + h*Dd + lane*4];
        float w = sc[k] * inv;
        o0 += w*bf2f(vu.x); o1 += w*bf2f(vu.y); o2 += w*bf2f(vu.z); o3 += w*bf2f(vu.w);
    }
    ushort4 ou; ou.x=f2bf(o0); ou.y=f2bf(o1); ou.z=f2bf(o2); ou.w=f2bf(o3);
    *(ushort4*)&att[(size_t)row*HD + h*Dd + lane*4] = ou;
}

// ---------------------------------------------------------------------------
__global__ __launch_bounds__(64)
void final_kernel(const float* __restrict__ h, const float* __restrict__ fcw,
                  const float* __restrict__ fcb, const float* __restrict__ stats,
                  float* __restrict__ out) {
    int row = blockIdx.x, lane = threadIdx.x;
    const float4 hv = *(const float4*)(h + (size_t)row*Cc + lane*4);
    float a0=0, a1=0, a2=0;
    const float hx[4] = {hv.x, hv.y, hv.z, hv.w};
    #pragma unroll
    for (int i = 0; i < 4; ++i) {
        int c = lane*4 + i;
        a0 += hx[i]*fcw[c*3+0]; a1 += hx[i]*fcw[c*3+1]; a2 += hx[i]*fcw[c*3+2];
    }
    #pragma unroll
    for (int s = 32; s > 0; s >>= 1) {
        a0 += __shfl_xor(a0, s); a1 += __shfl_xor(a1, s); a2 += __shfl_xor(a2, s);
    }
    if (lane == 0) {
        out[row*3+0] = a0 + fcb[0];
        out[row*3+1] = a1 + fcb[1];
        out[row*3+2] = a2 + fcb[2];
        if (row == 0)
            out[(size_t)Mrows*3] =
                (stats[0] + stats[1]) * (0.5f / ((float)Mrows * (float)Cc));
    }
}

// ---------------------------------------------------------------------------
extern "C" void kernel_launch(void* const* d_in, const int* in_sizes, int n_in,
                              void* d_out, int out_size, void* d_ws, size_t ws_size,
                              hipStream_t stream) {
    (void)in_sizes; (void)n_in; (void)out_size; (void)ws_size;
    const float* jf     = (const float*)d_in[0];
    const float* wq     = (const float*)d_in[1];
    const float* wk     = (const float*)d_in[2];
    const float* wv     = (const float*)d_in[3];
    const float* wp     = (const float*)d_in[4];
    const float* wsw    = (const float*)d_in[5];
    const float* wskip0 = (const float*)d_in[6];
    const float* fcw    = (const float*)d_in[7];
    const float* fcb    = (const float*)d_in[8];
    float* out = (float*)d_out;

    char* wsb = (char*)d_ws;
    unsigned short* QKVb  = (unsigned short*)(wsb + OFF_QKV);
    unsigned short* attb  = (unsigned short*)(wsb + OFF_ATT);
    float*          Tm    = (float*)(wsb + OFF_T);
    float*          G     = (float*)(wsb + OFF_G);
    unsigned short* jfb   = (unsigned short*)(wsb + OFF_JFB);
    unsigned short* h1b   = (unsigned short*)(wsb + OFF_H1B);
    float*          h2f   = (float*)(wsb + OFF_H2F);
    unsigned short* wqkvT = (unsigned short*)(wsb + OFF_WQKVT);
    unsigned short* fbt   = (unsigned short*)(wsb + OFF_FBT);
    float*          Wvp   = (float*)(wsb + OFF_WVP);
    float*          vproj = (float*)(wsb + OFF_VPROJ);
    float*          crd   = (float*)(wsb + OFF_CRD);
    int*            nbr0  = (int*)(wsb + OFF_NBR0);
    int*            nbr1  = (int*)(wsb + OFF_NBR1);
    float*          stats = (float*)(wsb + OFF_STAT);

    zero_stats_kernel<<<1, 64, 0, stream>>>(stats);

    // ---- weight/input conversion (bf16, B^T layouts) ----
    cvt_bf16_kernel<<<(Mrows*Cc/4 + 255)/256, 256, 0, stream>>>(jf, jfb, Mrows*Cc/4);
    for (int l = 0; l < 2; ++l) {
        unsigned short* wt = wqkvT + (size_t)l*QKVN*Cc;
        transpose_cvt_kernel<<<dim3(HD/32, Cc/32), 256, 0, stream>>>(
            wq + (size_t)l*Cc*HD, HD, wt + 0*(size_t)HD*Cc, Cc);
        transpose_cvt_kernel<<<dim3(HD/32, Cc/32), 256, 0, stream>>>(
            wk + (size_t)l*Cc*HD, HD, wt + 1*(size_t)HD*Cc, Cc);
        transpose_cvt_kernel<<<dim3(HD/32, Cc/32), 256, 0, stream>>>(
            wv + (size_t)l*Cc*HD, HD, wt + 2*(size_t)HD*Cc, Cc);
        unsigned short* fb = fbt + (size_t)l*Cc*KFUSE;
        transpose_cvt_kernel<<<dim3(Cc/32, HD/32), 256, 0, stream>>>(
            wp + (size_t)l*HD*Cc, Cc, fb + 0, KFUSE);
        transpose_cvt_kernel<<<dim3(Cc/32, Cc/32), 256, 0, stream>>>(
            wsw + (size_t)l*Cc*Cc, Cc, fb + HD, KFUSE);
        transpose_cvt_kernel<<<dim3(Cc/32, Cc/32), 256, 0, stream>>>(
            wskip0, Cc, fb + HD + Cc, KFUSE);
    }

    // ---- precise path precompute (layer 0 only) ----
    g_kernel<<<dim3(8, 64), 64, 0, stream>>>(wq, wk, G);
    sgemm_kernel<<<dim3(Mrows/128, HD/64), 256, 0, stream>>>(jf, Cc, G, HD, Tm, HD, Cc);
    wvp_kernel<<<8, 256, 0, stream>>>(wv, wp, Wvp);
    vproj_kernel<<<Mrows, 64, 0, stream>>>(jf, Wvp, vproj);

    // ---- layer 0 ----
    knn_kernel<<<Bb, 64, 0, stream>>>(jf, Cc, nbr0);
    precise_kernel<<<Mrows, 64, 0, stream>>>(Tm, jf, nbr0, vproj, wsw, wskip0, crd);
    gemm_bt_kernel<128,128,32,1,false,true><<<dim3(Mrows/128, QKVN/128), 256, 0, stream>>>(
        jfb, Cc, Cc, jfb, Cc, 0, jfb, Cc, 0, wqkvT, Cc, QKVb, QKVN, nullptr);
    attn_kernel<<<Mrows*Hh, 64, 0, stream>>>(QKVb, nbr0, attb);
    gemm_bt_kernel<64,64,64,3,true,true><<<dim3(Mrows/64, Cc/64), 256, 0, stream>>>(
        attb, HD, HD, jfb, Cc, Cc, jfb, Cc, Cc, fbt, KFUSE, h1b, Cc, &stats[0]);

    // ---- layer 1 ----
    knn_kernel<<<Bb, 64, 0, stream>>>(crd, 3, nbr1);
    gemm_bt_kernel<128,128,32,1,false,true><<<dim3(Mrows/128, QKVN/128), 256, 0, stream>>>(
        h1b, Cc, Cc, h1b, Cc, 0, h1b, Cc, 0, wqkvT + (size_t)QKVN*Cc, Cc, QKVb, QKVN, nullptr);
    attn_kernel<<<Mrows*Hh, 64, 0, stream>>>(QKVb, nbr1, attb);
    gemm_bt_kernel<64,64,64,3,true,false><<<dim3(Mrows/64, Cc/64), 256, 0, stream>>>(
        attb, HD, HD, h1b, Cc, Cc, jfb, Cc, Cc, fbt + (size_t)Cc*KFUSE, KFUSE, h2f, Cc, &stats[1]);

    // ---- final ----
    final_kernel<<<Mrows, 64, 0, stream>>>(h2f, fcw, fcb, stats, out);
}

// Round 3
// 371.617 us; speedup vs baseline: 2.6176x; 1.1808x over previous
//
#include <hip/hip_runtime.h>
#include <hip/hip_bf16.h>
#include <math.h>

namespace {
constexpr int Bb = 256, Jj = 21, Cc = 256, Hh = 8, Dd = 256;
constexpr int Mrows = Bb * Jj;      // 5376
constexpr int HD    = Hh * Dd;      // 2048
constexpr int QKVN  = 3 * HD;       // 6144
constexpr int KNN   = 8;
constexpr int KFUSE = HD + Cc + Cc; // 2560

// ---- workspace byte offsets (all 256-aligned) ----
constexpr size_t OFF_QKV   = 0;                                   // bf16 5376x6144
constexpr size_t OFF_ATT   = OFF_QKV   + (size_t)Mrows*QKVN*2;    // bf16 5376x2048
constexpr size_t OFF_T     = OFF_ATT   + (size_t)Mrows*HD*2;      // f32  5376x2048
constexpr size_t OFF_G     = OFF_T     + (size_t)Mrows*HD*4;      // f32  256x2048
constexpr size_t OFF_JFB   = OFF_G     + (size_t)Cc*HD*4;         // bf16 5376x256
constexpr size_t OFF_H1B   = OFF_JFB   + (size_t)Mrows*Cc*2;      // bf16 5376x256
constexpr size_t OFF_H2F   = OFF_H1B   + (size_t)Mrows*Cc*2;      // f32  5376x256
constexpr size_t OFF_WQKVT = OFF_H2F   + (size_t)Mrows*Cc*4;      // bf16 2x6144x256
constexpr size_t OFF_FBT   = OFF_WQKVT + (size_t)2*QKVN*Cc*2;     // bf16 2x256x2560
constexpr size_t OFF_WVP   = OFF_FBT   + (size_t)2*Cc*KFUSE*2;    // f32  256x24
constexpr size_t OFF_VPROJ = OFF_WVP   + (size_t)Hh*Cc*3*4;       // f32  5376x24
constexpr size_t OFF_CRD   = OFF_VPROJ + (size_t)Mrows*24*4;      // f32  5376x3
constexpr size_t OFF_NBR0  = OFF_CRD   + (size_t)Mrows*3*4 + 160; // int  5376x8
constexpr size_t OFF_NBR1  = OFF_NBR0  + (size_t)Mrows*KNN*4;
constexpr size_t OFF_STAT  = OFF_NBR1  + (size_t)Mrows*KNN*4;     // 2 f32
} // namespace

typedef short short8 __attribute__((ext_vector_type(8)));
typedef unsigned short u16x8 __attribute__((ext_vector_type(8)));
typedef float f32x4 __attribute__((ext_vector_type(4)));

__device__ __forceinline__ unsigned short f2bf(float x) {
    unsigned int u = __float_as_uint(x);
    u = u + 0x7fffu + ((u >> 16) & 1u);            // round-to-nearest-even
    return (unsigned short)(u >> 16);
}
__device__ __forceinline__ float bf2f(unsigned short b) {
    return __uint_as_float(((unsigned int)b) << 16);
}

// ---------------------------------------------------------------------------
// exact stable-argsort kNN: ranks 1..8 by (d2, index) ascending
__global__ __launch_bounds__(64)
void knn_kernel(const float* __restrict__ src, int ld, int* __restrict__ nbr) {
    int b = blockIdx.x;
    __shared__ float cs[Jj][3];
    int t = threadIdx.x;
    if (t < Jj) {
        const float* p = src + (size_t)(b * Jj + t) * ld;
        cs[t][0] = p[0]; cs[t][1] = p[1]; cs[t][2] = p[2];
    }
    __syncthreads();
    if (t < Jj) {
        float x = cs[t][0], y = cs[t][1], z = cs[t][2];
        float d2[Jj];
        #pragma unroll
        for (int jj = 0; jj < Jj; ++jj) {
            float dx = x - cs[jj][0], dy = y - cs[jj][1], dz = z - cs[jj][2];
            d2[jj] = dx*dx + dy*dy + dz*dz;
        }
        unsigned int used = 0u;
        int out_base = (b * Jj + t) * KNN;
        #pragma unroll
        for (int r = 0; r <= KNN; ++r) {
            int best = -1; float bd = INFINITY;
            #pragma unroll
            for (int jj = 0; jj < Jj; ++jj)
                if (!((used >> jj) & 1u) && d2[jj] < bd) { bd = d2[jj]; best = jj; }
            used |= (1u << best);
            if (r > 0) nbr[out_base + r - 1] = best;
        }
    }
}

// ---------------------------------------------------------------------------
// fp32 -> bf16 elementwise (n4 = n/4)
__global__ __launch_bounds__(256)
void cvt_bf16_kernel(const float* __restrict__ in, unsigned short* __restrict__ out, int n4) {
    int i = blockIdx.x * 256 + threadIdx.x;
    if (i < n4) {
        float4 v = ((const float4*)in)[i];
        ushort4 o; o.x = f2bf(v.x); o.y = f2bf(v.y); o.z = f2bf(v.z); o.w = f2bf(v.w);
        ((ushort4*)out)[i] = o;
    }
}

// ---------------------------------------------------------------------------
// ONE kernel for all 12 weight transposes (fp32 [K][N] -> bf16 [N][K]) + stats
// zeroing. Tile map: bids [0,3072) = 6 QKV transposes (512 tiles each),
// [3072,4096) = 2 wp (512 each), [4096,4352) = ws l0/l1, wskip l0/l1 (64 each).
__global__ __launch_bounds__(256)
void prep_weights_kernel(const float* __restrict__ wq, const float* __restrict__ wk,
                         const float* __restrict__ wv, const float* __restrict__ wp,
                         const float* __restrict__ wsw, const float* __restrict__ wsk,
                         unsigned short* __restrict__ wqkvT,
                         unsigned short* __restrict__ fbt, float* __restrict__ stats) {
    int bid = blockIdx.x;
    if (bid == 0 && threadIdx.x < 2) stats[threadIdx.x] = 0.0f;

    const float* src; unsigned short* dst;
    int ldin, ldout, tilesX, tile;
    constexpr size_t CH = (size_t)Cc * HD;
    if (bid < 3072) {
        int op = bid >> 9; tile = bid & 511; tilesX = 64;
        ldin = HD; ldout = Cc;
        const float* s3[3] = {wq, wk, wv};
        src = s3[op % 3] + (size_t)(op / 3) * CH;
        dst = wqkvT + (size_t)(op % 3) * HD * Cc + (size_t)(op / 3) * QKVN * Cc;
    } else if (bid < 4096) {
        int op = (bid - 3072) >> 9; tile = (bid - 3072) & 511; tilesX = 8;
        ldin = Cc; ldout = KFUSE;
        src = wp + (size_t)op * HD * Cc;
        dst = fbt + (size_t)op * Cc * KFUSE;
    } else {
        int q = bid - 4096; int op = q >> 6; tile = q & 63; tilesX = 8;
        ldin = Cc; ldout = KFUSE;
        const float* s4[4] = {wsw, wsw + (size_t)Cc * Cc, wsk, wsk};
        src = s4[op];
        dst = fbt + (size_t)(op & 1) * Cc * KFUSE + HD + (size_t)(op >> 1) * Cc;
    }
    int bx = tile % tilesX, by = tile / tilesX;
    int n0 = bx * 32, k0 = by * 32;

    __shared__ float t[32][33];
    int r = threadIdx.x >> 3, c4 = (threadIdx.x & 7) * 4;
    float4 v = *(const float4*)&src[(size_t)(k0 + r) * ldin + n0 + c4];
    t[r][c4+0] = v.x; t[r][c4+1] = v.y; t[r][c4+2] = v.z; t[r][c4+3] = v.w;
    __syncthreads();
    ushort4 o;
    o.x = f2bf(t[c4+0][r]); o.y = f2bf(t[c4+1][r]);
    o.z = f2bf(t[c4+2][r]); o.w = f2bf(t[c4+3][r]);
    *(ushort4*)&dst[(size_t)(n0 + r) * ldout + k0 + c4] = o;
}

// ---------------------------------------------------------------------------
// G[c][h*256+c'] = sum_d wq[c][h*256+d] * wk[c'][h*256+d]   (fp32, exact path)
__global__ __launch_bounds__(64)
void g_kernel(const float* __restrict__ wq, const float* __restrict__ wk,
              float* __restrict__ G) {
    int h = blockIdx.x, cg = blockIdx.y;
    __shared__ float q[4][256];
    int l = threadIdx.x;
    #pragma unroll
    for (int ci = 0; ci < 4; ++ci)
        *(float4*)&q[ci][l*4] = *(const float4*)&wq[(size_t)(cg*4+ci)*HD + h*256 + l*4];
    __syncthreads();
    #pragma unroll
    for (int i = 0; i < 4; ++i) {
        int cp = l + i*64;
        const float* kr = &wk[(size_t)cp*HD + h*256];
        float a0=0,a1=0,a2=0,a3=0;
        for (int d = 0; d < 256; d += 4) {
            float4 kv = *(const float4*)&kr[d];
            a0 += q[0][d]*kv.x + q[0][d+1]*kv.y + q[0][d+2]*kv.z + q[0][d+3]*kv.w;
            a1 += q[1][d]*kv.x + q[1][d+1]*kv.y + q[1][d+2]*kv.z + q[1][d+3]*kv.w;
            a2 += q[2][d]*kv.x + q[2][d+1]*kv.y + q[2][d+2]*kv.z + q[2][d+3]*kv.w;
            a3 += q[3][d]*kv.x + q[3][d+1]*kv.y + q[3][d+2]*kv.z + q[3][d+3]*kv.w;
        }
        G[(size_t)(cg*4+0)*HD + h*256 + cp] = a0;
        G[(size_t)(cg*4+1)*HD + h*256 + cp] = a1;
        G[(size_t)(cg*4+2)*HD + h*256 + cp] = a2;
        G[(size_t)(cg*4+3)*HD + h*256 + cp] = a3;
    }
}

// ---------------------------------------------------------------------------
// Wvp2[e][h*3+c] = sum_d wv[e][h*256+d] * wp[h*256+d][c].  grid (8), 256 thr
__global__ __launch_bounds__(256)
void wvp_kernel(const float* __restrict__ wv, const float* __restrict__ wp,
                float* __restrict__ Wvp2) {
    int h = blockIdx.x;
    __shared__ float wpc[256][3];
    int t = threadIdx.x;
    const float* p = &wp[(size_t)(h*256 + t) * Cc];
    wpc[t][0] = p[0]; wpc[t][1] = p[1]; wpc[t][2] = p[2];
    __syncthreads();
    const float* vr = &wv[(size_t)t*HD + h*256];
    float a0=0, a1=0, a2=0;
    for (int d = 0; d < 256; ++d) {
        float v = vr[d];
        a0 += v*wpc[d][0]; a1 += v*wpc[d][1]; a2 += v*wpc[d][2];
    }
    float* o = &Wvp2[(size_t)t*24 + h*3];
    o[0]=a0; o[1]=a1; o[2]=a2;
}

// ---------------------------------------------------------------------------
// vproj[j][o] = sum_e h0[j][e] * Wvp2[e][o], o<24.  8 rows/block, 256 thr.
__global__ __launch_bounds__(256)
void vproj_kernel(const float* __restrict__ h0, const float* __restrict__ Wvp2,
                  float* __restrict__ vproj) {
    __shared__ float hr[8][256];
    __shared__ float wl[6144];
    int t = threadIdx.x;
    int j0 = blockIdx.x * 8;
    #pragma unroll
    for (int i = 0; i < 6; ++i)
        *(float4*)&wl[t*4 + i*1024] = *(const float4*)&Wvp2[t*4 + i*1024];
    {
        int r = t >> 5, c = (t & 31) * 8;
        const float* src = &h0[(size_t)(j0 + r)*Cc + c];
        *(float4*)&hr[r][c]   = *(const float4*)src;
        *(float4*)&hr[r][c+4] = *(const float4*)(src + 4);
    }
    __syncthreads();
    int r = t >> 5, o = t & 31;
    if (o < 24) {
        float a = 0.0f;
        for (int e = 0; e < 256; ++e) a += hr[r][e] * wl[e*24 + o];
        vproj[(size_t)(j0 + r)*24 + o] = a;
    }
}

// ---------------------------------------------------------------------------
// precise layer-0 coords: per row i, softmax(leaky(T_i . h0_nbr /16)) over K,
// coords = relu(sum_k w * vproj[nbr] + h0_i.(ws0+wskip0)[:,c])
__global__ __launch_bounds__(64)
void precise_kernel(const float* __restrict__ T, const float* __restrict__ h0,
                    const int* __restrict__ nbr, const float* __restrict__ vproj,
                    const float* __restrict__ wsl, const float* __restrict__ wsk,
                    float* __restrict__ coords) {
    int i = blockIdx.x;
    int b = i / Jj;
    int l = threadIdx.x;
    __shared__ float Ts[8][260];
    __shared__ float nb[8][260];
    __shared__ float hi[256];
    #pragma unroll
    for (int u = 0; u < 8; ++u) {
        int idx = u*64 + l;
        float4 v = *(const float4*)&T[(size_t)i*HD + idx*4];
        int hh = idx >> 6, dd = (idx & 63) * 4;
        *(float4*)&Ts[hh][dd] = v;
    }
    *(float4*)&hi[l*4] = *(const float4*)&h0[(size_t)i*Cc + l*4];
    int kq = l >> 3, s = l & 7;
    int njs = nbr[i*KNN + kq];
    const float* nrow = &h0[(size_t)(b*Jj + njs)*Cc];
    #pragma unroll
    for (int u = 0; u < 8; ++u)
        *(float4*)&nb[kq][(s*8+u)*4] = *(const float4*)&nrow[(s*8+u)*4];
    __syncthreads();

    int k = l >> 3, h = l & 7;
    float sacc = 0;
    for (int d = 0; d < 256; ++d) sacc += Ts[h][d] * nb[k][d];
    float sc = sacc * 0.0625f;
    sc = (sc >= 0.0f) ? sc : 0.2f * sc;
    float m = sc;
    m = fmaxf(m, __shfl_xor(m, 8));
    m = fmaxf(m, __shfl_xor(m, 16));
    m = fmaxf(m, __shfl_xor(m, 32));
    float e = expf(sc - m);
    float den = e;
    den += __shfl_xor(den, 8); den += __shfl_xor(den, 16); den += __shfl_xor(den, 32);
    float w = e / den;

    int njk = nbr[i*KNN + k];
    const float* vp = &vproj[(size_t)(b*Jj + njk)*24 + h*3];
    float t0 = w * vp[0], t1 = w * vp[1], t2 = w * vp[2];
    #pragma unroll
    for (int u = 0; u < 4; ++u) {
        int e4 = l*4 + u;
        float hv = hi[e4];
        const float* w1 = &wsl[(size_t)e4*Cc];
        const float* w2 = &wsk[(size_t)e4*Cc];
        t0 += hv * (w1[0] + w2[0]);
        t1 += hv * (w1[1] + w2[1]);
        t2 += hv * (w1[2] + w2[2]);
    }
    #pragma unroll
    for (int sft = 1; sft < 64; sft <<= 1) {
        t0 += __shfl_xor(t0, sft); t1 += __shfl_xor(t1, sft); t2 += __shfl_xor(t2, sft);
    }
    if (l == 0) {
        coords[i*3+0] = fmaxf(t0, 0.0f);
        coords[i*3+1] = fmaxf(t1, 0.0f);
        coords[i*3+2] = fmaxf(t2, 0.0f);
    }
}

// ---------------------------------------------------------------------------
// fp32 GEMM 128x128, BK=16, 256 threads, 8x8 microtile. A[Mx256] @ W[256x2048]
__global__ __launch_bounds__(256)
void sgemm128_kernel(const float* __restrict__ A, const float* __restrict__ W,
                     float* __restrict__ C) {
    constexpr int BM = 128, BN = 128, BK = 16;
    __shared__ float As[BK][BM + 4];
    __shared__ float Ws[BK][BN + 4];
    int tid = threadIdx.x;
    int bm = blockIdx.x * BM, bn = blockIdx.y * BN;
    int ar = tid >> 1, ac = (tid & 1) * 8;
    int wr = tid >> 4, wc = (tid & 15) * 8;
    int ty = tid >> 4, tx = tid & 15;
    float acc[8][8] = {};
    for (int k0 = 0; k0 < Cc; k0 += BK) {
        const float* ap = A + (size_t)(bm + ar) * Cc + k0 + ac;
        float4 a0 = *(const float4*)ap;
        float4 a1 = *(const float4*)(ap + 4);
        As[ac+0][ar] = a0.x; As[ac+1][ar] = a0.y; As[ac+2][ar] = a0.z; As[ac+3][ar] = a0.w;
        As[ac+4][ar] = a1.x; As[ac+5][ar] = a1.y; As[ac+6][ar] = a1.z; As[ac+7][ar] = a1.w;
        const float* wp_ = W + (size_t)(k0 + wr) * HD + bn + wc;
        *(float4*)&Ws[wr][wc]     = *(const float4*)wp_;
        *(float4*)&Ws[wr][wc + 4] = *(const float4*)(wp_ + 4);
        __syncthreads();
        #pragma unroll
        for (int kk = 0; kk < BK; ++kk) {
            float4 av0 = *(const float4*)&As[kk][ty*8];
            float4 av1 = *(const float4*)&As[kk][ty*8 + 4];
            float4 bv0 = *(const float4*)&Ws[kk][tx*8];
            float4 bv1 = *(const float4*)&Ws[kk][tx*8 + 4];
            float a[8] = {av0.x,av0.y,av0.z,av0.w,av1.x,av1.y,av1.z,av1.w};
            float b[8] = {bv0.x,bv0.y,bv0.z,bv0.w,bv1.x,bv1.y,bv1.z,bv1.w};
            #pragma unroll
            for (int i = 0; i < 8; ++i)
                #pragma unroll
                for (int j = 0; j < 8; ++j)
                    acc[i][j] += a[i] * b[j];
        }
        __syncthreads();
    }
    #pragma unroll
    for (int i = 0; i < 8; ++i) {
        float* cp = C + (size_t)(bm + ty*8 + i) * HD + bn + tx*8;
        float4 o0 = {acc[i][0], acc[i][1], acc[i][2], acc[i][3]};
        float4 o1 = {acc[i][4], acc[i][5], acc[i][6], acc[i][7]};
        *(float4*)cp = o0;
        *(float4*)(cp + 4) = o1;
    }
}

// ---------------------------------------------------------------------------
// bf16 MFMA GEMM, B^T input ([N][K]), segmented A along K, fp32 accum.
// 256 threads = 4 waves in 2x2; per-wave tile (BM/2)x(BN/2).
template<int BM, int BN, int BK, int NSEG, bool RELU_STATS, bool OUT_BF16>
__global__ __launch_bounds__(256)
void gemm_bt_kernel(const unsigned short* __restrict__ A0, int lda0, int klen0,
                    const unsigned short* __restrict__ A1, int lda1, int klen1,
                    const unsigned short* __restrict__ A2, int lda2, int klen2,
                    const unsigned short* __restrict__ Bt, int ldb,
                    void* __restrict__ Cv, int ldc, float* __restrict__ stat) {
    constexpr int WM = BM/2, WN = BN/2;
    constexpr int MW = WM/16, NW = WN/16, KW = BK/32;
    constexpr int CHUNK = BM*BK/8;       // 16B chunks per tile (BM==BN)
    constexpr int KB8 = BK/8;
    __shared__ unsigned short As[BM*BK];
    __shared__ unsigned short Bs[BN*BK];
    __shared__ float red[4];

    int tid = threadIdx.x;
    int wid = tid >> 6, lane = tid & 63;
    int wr = wid >> 1, wc = wid & 1;
    int bm = blockIdx.x * BM, bn = blockIdx.y * BN;

    f32x4 acc[MW][NW];
    #pragma unroll
    for (int m = 0; m < MW; ++m)
        #pragma unroll
        for (int n = 0; n < NW; ++n)
            acc[m][n] = (f32x4){0.f, 0.f, 0.f, 0.f};

    const unsigned short* Aseg[3] = {A0, A1, A2};
    const int ldas[3] = {lda0, lda1, lda2};
    const int klens[3] = {klen0, klen1, klen2};

    int kglob = 0;
    for (int seg = 0; seg < NSEG; ++seg) {
        const unsigned short* A = Aseg[seg];
        const int lda = ldas[seg];
        const int klen = klens[seg];
        for (int k0 = 0; k0 < klen; k0 += BK) {
            #pragma unroll
            for (int it = 0; it < CHUNK/256; ++it) {
                int c = tid + it*256;
                int row = c / KB8, kp = c % KB8;
                __builtin_amdgcn_global_load_lds(
                    (const __attribute__((address_space(1))) unsigned int*)
                        (A + (size_t)(bm + row)*lda + k0 + kp*8),
                    (__attribute__((address_space(3))) unsigned int*)(As + c*8),
                    16, 0, 0);
            }
            #pragma unroll
            for (int it = 0; it < CHUNK/256; ++it) {
                int c = tid + it*256;
                int row = c / KB8, kp = c % KB8;
                __builtin_amdgcn_global_load_lds(
                    (const __attribute__((address_space(1))) unsigned int*)
                        (Bt + (size_t)(bn + row)*ldb + kglob + k0 + kp*8),
                    (__attribute__((address_space(3))) unsigned int*)(Bs + c*8),
                    16, 0, 0);
            }
            __syncthreads();
            #pragma unroll
            for (int kp = 0; kp < KW; ++kp) {
                short8 af[MW], bf[NW];
                #pragma unroll
                for (int m = 0; m < MW; ++m)
                    af[m] = *(const short8*)&As[(wr*WM + m*16 + (lane & 15))*BK
                                               + kp*32 + (lane >> 4)*8];
                #pragma unroll
                for (int n = 0; n < NW; ++n)
                    bf[n] = *(const short8*)&Bs[(wc*WN + n*16 + (lane & 15))*BK
                                               + kp*32 + (lane >> 4)*8];
                #pragma unroll
                for (int m = 0; m < MW; ++m)
                    #pragma unroll
                    for (int n = 0; n < NW; ++n)
                        acc[m][n] = __builtin_amdgcn_mfma_f32_16x16x32_bf16(
                            af[m], bf[n], acc[m][n], 0, 0, 0);
            }
            __syncthreads();
        }
        kglob += klen;
    }

    // epilogue: C/D layout col=lane&15, row=(lane>>4)*4+j
    int cr = (lane >> 4)*4, cc = lane & 15;
    float bsum = 0.0f;
    #pragma unroll
    for (int m = 0; m < MW; ++m)
        #pragma unroll
        for (int n = 0; n < NW; ++n)
            #pragma unroll
            for (int j = 0; j < 4; ++j) {
                float v = acc[m][n][j];
                if (RELU_STATS) { v = fmaxf(v, 0.0f); bsum += v; }
                size_t row = bm + wr*WM + m*16 + cr + j;
                size_t col = bn + wc*WN + n*16 + cc;
                if (OUT_BF16) ((unsigned short*)Cv)[row*ldc + col] = f2bf(v);
                else          ((float*)Cv)[row*ldc + col] = v;
            }
    if (RELU_STATS) {
        #pragma unroll
        for (int sft = 1; sft < 64; sft <<= 1) bsum += __shfl_xor(bsum, sft);
        if (lane == 0) red[wid] = bsum;
        __syncthreads();
        if (tid == 0) atomicAdd(stat, red[0] + red[1] + red[2] + red[3]);
    }
}

// ---------------------------------------------------------------------------
// attention: one wave per (row, head-pair); 32 lanes per head, ushort8 loads.
__global__ __launch_bounds__(64)
void attn_kernel(const unsigned short* __restrict__ QKV,
                 const int* __restrict__ nbr, unsigned short* __restrict__ att) {
    int gid = blockIdx.x;
    int hp = gid & 3, row = gid >> 2, b = row / Jj;
    int lane = threadIdx.x;
    int h = hp*2 + (lane >> 5);
    int d0 = (lane & 31) * 8;

    u16x8 qu = *(const u16x8*)&QKV[(size_t)row*QKVN + h*Dd + d0];
    float qf[8];
    #pragma unroll
    for (int i = 0; i < 8; ++i) qf[i] = bf2f(qu[i]);
    const int* np_ = nbr + row * KNN;

    float sc[KNN]; int nb[KNN];
    #pragma unroll
    for (int k = 0; k < KNN; ++k) {
        int n = np_[k]; nb[k] = n;
        u16x8 ku = *(const u16x8*)&QKV[(size_t)(b*Jj + n)*QKVN + HD + h*Dd + d0];
        float p = 0;
        #pragma unroll
        for (int i = 0; i < 8; ++i) p += qf[i] * bf2f(ku[i]);
        #pragma unroll
        for (int s = 1; s < 32; s <<= 1) p += __shfl_xor(p, s);
        sc[k] = p;
    }
    float mx = -INFINITY;
    #pragma unroll
    for (int k = 0; k < KNN; ++k) {
        float s = sc[k] * 0.0625f;
        s = (s >= 0.0f) ? s : 0.2f * s;
        sc[k] = s; mx = fmaxf(mx, s);
    }
    float den = 0.0f;
    #pragma unroll
    for (int k = 0; k < KNN; ++k) { sc[k] = expf(sc[k] - mx); den += sc[k]; }
    float inv = 1.0f / den;
    float o[8] = {};
    #pragma unroll
    for (int k = 0; k < KNN; ++k) {
        u16x8 vu = *(const u16x8*)&QKV[(size_t)(b*Jj + nb[k])*QKVN + 2*HD + h*Dd + d0];
        float w = sc[k] * inv;
        #pragma unroll
        for (int i = 0; i < 8; ++i) o[i] += w * bf2f(vu[i]);
    }
    u16x8 ou;
    #pragma unroll
    for (int i = 0; i < 8; ++i) ou[i] = f2bf(o[i]);
    *(u16x8*)&att[(size_t)row*HD + h*Dd + d0] = ou;
}

// ---------------------------------------------------------------------------
__global__ __launch_bounds__(64)
void final_kernel(const float* __restrict__ h, const float* __restrict__ fcw,
                  const float* __restrict__ fcb, const float* __restrict__ stats,
                  float* __restrict__ out) {
    int row = blockIdx.x, lane = threadIdx.x;
    const float4 hv = *(const float4*)(h + (size_t)row*Cc + lane*4);
    float a0=0, a1=0, a2=0;
    const float hx[4] = {hv.x, hv.y, hv.z, hv.w};
    #pragma unroll
    for (int i = 0; i < 4; ++i) {
        int c = lane*4 + i;
        a0 += hx[i]*fcw[c*3+0]; a1 += hx[i]*fcw[c*3+1]; a2 += hx[i]*fcw[c*3+2];
    }
    #pragma unroll
    for (int s = 32; s > 0; s >>= 1) {
        a0 += __shfl_xor(a0, s); a1 += __shfl_xor(a1, s); a2 += __shfl_xor(a2, s);
    }
    if (lane == 0) {
        out[row*3+0] = a0 + fcb[0];
        out[row*3+1] = a1 + fcb[1];
        out[row*3+2] = a2 + fcb[2];
        if (row == 0)
            out[(size_t)Mrows*3] =
                (stats[0] + stats[1]) * (0.5f / ((float)Mrows * (float)Cc));
    }
}

// ---------------------------------------------------------------------------
extern "C" void kernel_launch(void* const* d_in, const int* in_sizes, int n_in,
                              void* d_out, int out_size, void* d_ws, size_t ws_size,
                              hipStream_t stream) {
    (void)in_sizes; (void)n_in; (void)out_size; (void)ws_size;
    const float* jf     = (const float*)d_in[0];
    const float* wq     = (const float*)d_in[1];
    const float* wk     = (const float*)d_in[2];
    const float* wv     = (const float*)d_in[3];
    const float* wp     = (const float*)d_in[4];
    const float* wsw    = (const float*)d_in[5];
    const float* wskip0 = (const float*)d_in[6];
    const float* fcw    = (const float*)d_in[7];
    const float* fcb    = (const float*)d_in[8];
    float* out = (float*)d_out;

    char* wsb = (char*)d_ws;
    unsigned short* QKVb  = (unsigned short*)(wsb + OFF_QKV);
    unsigned short* attb  = (unsigned short*)(wsb + OFF_ATT);
    float*          Tm    = (float*)(wsb + OFF_T);
    float*          G     = (float*)(wsb + OFF_G);
    unsigned short* jfb   = (unsigned short*)(wsb + OFF_JFB);
    unsigned short* h1b   = (unsigned short*)(wsb + OFF_H1B);
    float*          h2f   = (float*)(wsb + OFF_H2F);
    unsigned short* wqkvT = (unsigned short*)(wsb + OFF_WQKVT);
    unsigned short* fbt   = (unsigned short*)(wsb + OFF_FBT);
    float*          Wvp   = (float*)(wsb + OFF_WVP);
    float*          vproj = (float*)(wsb + OFF_VPROJ);
    float*          crd   = (float*)(wsb + OFF_CRD);
    int*            nbr0  = (int*)(wsb + OFF_NBR0);
    int*            nbr1  = (int*)(wsb + OFF_NBR1);
    float*          stats = (float*)(wsb + OFF_STAT);

    // ---- prep: all weight transposes (+stats zero), activations, precise path ----
    prep_weights_kernel<<<4352, 256, 0, stream>>>(wq, wk, wv, wp, wsw, wskip0,
                                                  wqkvT, fbt, stats);
    cvt_bf16_kernel<<<(Mrows*Cc/4 + 255)/256, 256, 0, stream>>>(jf, jfb, Mrows*Cc/4);
    g_kernel<<<dim3(8, 64), 64, 0, stream>>>(wq, wk, G);
    sgemm128_kernel<<<dim3(Mrows/128, HD/128), 256, 0, stream>>>(jf, G, Tm);
    wvp_kernel<<<8, 256, 0, stream>>>(wv, wp, Wvp);
    vproj_kernel<<<Mrows/8, 256, 0, stream>>>(jf, Wvp, vproj);

    // ---- layer 0 ----
    knn_kernel<<<Bb, 64, 0, stream>>>(jf, Cc, nbr0);
    precise_kernel<<<Mrows, 64, 0, stream>>>(Tm, jf, nbr0, vproj, wsw, wskip0, crd);
    gemm_bt_kernel<128,128,64,1,false,true><<<dim3(Mrows/128, QKVN/128), 256, 0, stream>>>(
        jfb, Cc, Cc, jfb, Cc, 0, jfb, Cc, 0, wqkvT, Cc, QKVb, QKVN, nullptr);
    attn_kernel<<<Mrows*4, 64, 0, stream>>>(QKVb, nbr0, attb);
    gemm_bt_kernel<64,64,64,3,true,true><<<dim3(Mrows/64, Cc/64), 256, 0, stream>>>(
        attb, HD, HD, jfb, Cc, Cc, jfb, Cc, Cc, fbt, KFUSE, h1b, Cc, &stats[0]);

    // ---- layer 1 ----
    knn_kernel<<<Bb, 64, 0, stream>>>(crd, 3, nbr1);
    gemm_bt_kernel<128,128,64,1,false,true><<<dim3(Mrows/128, QKVN/128), 256, 0, stream>>>(
        h1b, Cc, Cc, h1b, Cc, 0, h1b, Cc, 0, wqkvT + (size_t)QKVN*Cc, Cc, QKVb, QKVN, nullptr);
    attn_kernel<<<Mrows*4, 64, 0, stream>>>(QKVb, nbr1, attb);
    gemm_bt_kernel<64,64,64,3,true,false><<<dim3(Mrows/64, Cc/64), 256, 0, stream>>>(
        attb, HD, HD, h1b, Cc, Cc, jfb, Cc, Cc, fbt + (size_t)Cc*KFUSE, KFUSE, h2f, Cc, &stats[1]);

    // ---- final ----
    final_kernel<<<Mrows, 64, 0, stream>>>(h2f, fcw, fcb, stats, out);
}